// Round 10
// baseline (30350.845 us; speedup 1.0000x reference)
//
#include <hip/hip_runtime.h>
#include <math.h>

#define TPB 1024
#define NBLK 256

typedef unsigned short u16;
typedef unsigned char u8;
typedef float f32x4 __attribute__((ext_vector_type(4)));
typedef short s16x8 __attribute__((ext_vector_type(8)));
typedef unsigned int u32x4 __attribute__((ext_vector_type(4)));
typedef unsigned int u32x2 __attribute__((ext_vector_type(2)));

// ---------------- helpers ----------------
__device__ __forceinline__ u16 f2bf(float f) {
  unsigned u = __float_as_uint(f);
  unsigned r = (u + 0x7FFFu + ((u >> 16) & 1u)) >> 16;   // RNE
  return (u16)r;
}
__device__ __forceinline__ float bf2f(u16 b) { return __uint_as_float(((unsigned)b) << 16); }
__device__ __forceinline__ float sigm(float x) { return 1.f / (1.f + expf(-x)); }

__device__ __forceinline__ f32x4 mfma_bf16(s16x8 a, s16x8 b, f32x4 c) {
  return __builtin_amdgcn_mfma_f32_16x16x32_bf16(a, b, c, 0, 0, 0);
}

// int8 fixed-point h: q = rint(h*128), |h|<1. Decode q/128 is EXACT in bf16.
__device__ __forceinline__ unsigned pk2(unsigned wd, int j) {
  int b0 = ((int)(wd << ((3 - j) * 8))) >> 24;
  int b1 = ((int)(wd << ((2 - j) * 8))) >> 24;
  float f0 = (float)b0 * 0.0078125f;
  float f1 = (float)b1 * 0.0078125f;
  return (__float_as_uint(f0) >> 16) | (__float_as_uint(f1) & 0xFFFF0000u);
}
__device__ __forceinline__ s16x8 unpk8(u32x2 wv) {  // fc head only
  s16x8 o;
#pragma unroll
  for (int j = 0; j < 4; ++j) {
    int b0 = ((int)(wv[0] << ((3 - j) * 8))) >> 24;
    float f0 = (float)b0 * 0.0078125f;
    o[j] = (short)(__float_as_uint(f0) >> 16);
    int b1 = ((int)(wv[1] << ((3 - j) * 8))) >> 24;
    float f1 = (float)b1 * 0.0078125f;
    o[4 + j] = (short)(__float_as_uint(f1) >> 16);
  }
  return o;
}

// ---- asm memory ops. sc1 = device scope (meet at LLC); plain = cached.
__device__ __forceinline__ u32x4 ld_sc1_x4(const void* p) {
  u32x4 d;
  asm volatile("global_load_dwordx4 %0, %1, off sc1"
               : "=v"(d) : "v"((unsigned long long)p) : "memory");
  return d;
}
__device__ __forceinline__ unsigned ld_sc1_x1(const void* p) {
  unsigned d;
  asm volatile("global_load_dword %0, %1, off sc1"
               : "=v"(d) : "v"((unsigned long long)p) : "memory");
  return d;
}
__device__ __forceinline__ s16x8 ld_b16x8(const void* p) {  // cached (weights)
  s16x8 d;
  asm volatile("global_load_dwordx4 %0, %1, off"
               : "=v"(d) : "v"((unsigned long long)p) : "memory");
  return d;
}
__device__ __forceinline__ void st_sc1_x4(void* p, u32x4 v) {
  asm volatile("global_store_dwordx4 %0, %1, off sc1"
               :: "v"((unsigned long long)p), "v"(v) : "memory");
}
__device__ __forceinline__ void wait_vm0() { asm volatile("s_waitcnt vmcnt(0)" ::: "memory"); }
#define WAITVM(n) asm volatile("s_waitcnt vmcnt(" #n ")" ::: "memory")
__device__ __forceinline__ void pin(u32x4& v) { asm volatile("" : "+v"(v)); }
__device__ __forceinline__ void pin(unsigned& v) { asm volatile("" : "+v"(v)); }
__device__ __forceinline__ void pin(s16x8& v) { asm volatile("" : "+v"(v)); }

// ---------------- params ----------------
struct KParams {
  const float* x;          // [1024][336][16]
  float* out;              // [1024][168]
  unsigned long long* cx;  // per-M-GROUP barrier counters (16 groups, stride 256B)
  unsigned long long* cg;  // unused
  u8* h0h[2]; u8* h1h[2];  // h int8 fixed-point [16 ch][1024 r][32 B], ping-pong (sc1)
  const u16 *we0h, *we0l;  // [17][2048][32] (chunk 16 = x weights)
  const u16 *we1h, *we1l;  // [32][2048][32]
  const u16 *wd0h, *wd0l;  // [16][2048][32]
  const u16 *wd1h, *wd1l;  // [32][2048][32]
  const u16 *wfh;          // [16][256][32] (hi only)
  const float *be0, *be1, *bd0, *bd1, *wyp;  // permuted biases [2048], dec0 y-column [2048]
  const float *fcb1, *fcw2, *fcb2;           // raw fp32 from inputs
};

// ---------------- init kernels ----------------
__global__ void zero_ws(uint4* p, long n) {
  uint4 z = {0u, 0u, 0u, 0u};
  for (long i = (long)blockIdx.x * blockDim.x + threadIdx.x; i < n; i += (long)gridDim.x * blockDim.x)
    p[i] = z;
}

// Build fragment-major, gate-interleaved, hi/lo-split weights.
// dst[c][n'][kk], n' = h*4+g  (orig row n = g*512+h), k = c*32+kk.
__global__ void prep_w(const float* __restrict__ Wih, const float* __restrict__ Whh,
                       const float* __restrict__ bias,
                       u16* __restrict__ dhi, u16* __restrict__ dlo,
                       float* __restrict__ bias_p, float* __restrict__ wy_p,
                       int mode, int nchunks) {
  long total = (long)nchunks * 2048 * 32;
  for (long i = (long)blockIdx.x * blockDim.x + threadIdx.x; i < total; i += (long)gridDim.x * blockDim.x) {
    int kk = (int)(i & 31);
    long r1 = i >> 5;
    int n = (int)(r1 & 2047);
    int c = (int)(r1 >> 11);
    int h = n >> 2, g = n & 3;
    int no = g * 512 + h;
    float wv;
    if (mode == 0)      wv = (c < 16) ? Whh[no * 512 + c * 32 + kk] : (kk < 16 ? Wih[no * 16 + kk] : 0.f);
    else if (mode == 1) wv = (c < 16) ? Wih[no * 512 + c * 32 + kk] : Whh[no * 512 + (c - 16) * 32 + kk];
    else                wv = Whh[no * 512 + c * 32 + kk];
    u16 hb = f2bf(wv);
    dhi[i] = hb;
    dlo[i] = f2bf(wv - bf2f(hb));
    if (i < 2048) {
      int nn = (int)i, hh = nn >> 2, gg = nn & 3, noo = gg * 512 + hh;
      bias_p[nn] = bias[noo];
      if (mode == 2) wy_p[nn] = Wih[noo];  // dec_Wih0 is [2048][1]
    }
  }
}

__global__ void prep_fc(const float* __restrict__ W1, u16* __restrict__ dhi) {
  int total = 16 * 256 * 32;
  for (int i = blockIdx.x * blockDim.x + threadIdx.x; i < total; i += gridDim.x * blockDim.x) {
    int kk = i & 31, n = (i >> 5) & 255, c = i >> 13;
    dhi[i] = f2bf(W1[n * 512 + c * 32 + kk]);
  }
}

// ------------- m-group barrier: 16 blocks (all n-tiles of one m-tile) -------------
// All cross-block deps are m-row-local (verified r7).
__device__ __forceinline__ void gbar(const KParams& P, int mgrp, unsigned long long bi) {
  wait_vm0();       // this wave's sc1 stores are at the LLC
  __syncthreads();  // all 16 waves drained
  if (threadIdx.x == 0) {
    unsigned long long* ctr = &P.cx[mgrp * 32];
    __hip_atomic_fetch_add(ctr, 1ULL, __ATOMIC_RELAXED, __HIP_MEMORY_SCOPE_AGENT);
    unsigned long long t0 = __builtin_amdgcn_s_memrealtime();
    while (__hip_atomic_load(ctr, __ATOMIC_RELAXED, __HIP_MEMORY_SCOPE_AGENT) < bi * 16ULL) {
      __builtin_amdgcn_s_sleep(2);
      if (__builtin_amdgcn_s_memrealtime() - t0 > 300000000ULL) {  // ~3 s
        P.out[0] = 1e9f;  // sentinel: barrier timeout
        break;
      }
    }
  }
  __syncthreads();
}

// ---------------- fused gates GEMM + LSTM cell ----------------
// 64m x 128n tile, 256 blocks (mapping/slabs = champion), 1024 THREADS:
// 16 waves/block = 4 waves/SIMD. r9 (2 waves/SIMD) paid 1.32x and left
// MfmaUtil+VALUBusy at ~34% -> SIMDs still 2/3 idle on the
// ds_write->barrier->ds_read->MFMA chain. Grid is fixed at 1 block/CU, so
// block size is the only occupancy lever. Wave (w_m,w_n)=(w>>3,w&7) owns
// 32 rows x 16 cols: acc f32x4[2], bb[2][4] (32 VGPR), A dword/thread ->
// ~90 VGPR, under the 128-cap for 4 waves/SIMD (__launch_bounds__(1024,4)).
// Per stage/thread: 1 A (dword int8) + 4 B -- SAME counts as r9, so the
// queue-simulated vmcnt schedule carries over unchanged:
// s<=1:9; s<=NST-6:6; s==NST-5:5; else 4; last 0.
template <int NCT, bool TWOA, bool HASX, bool HASY>
__device__ __forceinline__ void lstm_phase(
    const KParams& P, int m_tile, int n_tile,
    const u8* A1h, const u8* A2h,
    const u16* WBh, const u16* WBl,
    const float* __restrict__ bias_p, const float* __restrict__ wyp, int t,
    float (&creg)[2], u8* Hh, char* smem, const float* yb) {
  constexpr int NST = NCT / 2;
  const int tid = threadIdx.x;
  const int w = tid >> 6, lane = tid & 63, r = lane & 15, q = lane >> 4;
  const int w_m = w >> 3, w_n = w & 7;
  const int m0 = m_tile * 64, n0 = n_tile * 128;
  u16* sA = (u16*)smem;  // 2 bufs x [2ch][64r][40] u16 = 20480 B (bf16 after predecode)
  const int rr = (tid >> 3) & 63, seg = tid & 7, chA = tid >> 9;

  f32x4 acc[2];
#pragma unroll
  for (int mr = 0; mr < 2; ++mr) acc[mr] = (f32x4){0.f, 0.f, 0.f, 0.f};

  unsigned ab[6];  // A 6-stage lookahead, 1 dword (4 int8)/thread/stage
  s16x8 bb[2][4];  // B 2-stage lookahead; i = ch*2 + hl
  const int a_elem = (m0 + rr) * 32 + seg * 4;          // bytes; + chunk*32768
  const int b_elem = (n0 + w_n * 16 + r) * 32 + q * 8;  // + chunk*65536

  auto issueA = [&](int s) {
    int c = s * 2 + chA;
    const u8* base = A1h;
    if (TWOA && c >= 16) { base = A2h; c -= 16; }
    ab[s % 6] = ld_sc1_x1(base + c * 32768 + a_elem);
  };
  auto issueB = [&](int s) {
#pragma unroll
    for (int i = 0; i < 4; ++i) {  // i = ch*2 + hl
      int ch = i >> 1, hl = i & 1;
      int c = s * 2 + ch;
      bb[s & 1][i] = ld_b16x8((hl ? WBl : WBh) + c * 65536 + b_elem);
    }
  };

  // prologue; FIFO order: A0 B0 A1 B1 A2 A3 A4 A5  (NST >= 6 always)
  issueA(0); issueB(0); issueA(1); issueB(1);
  issueA(2); issueA(3); issueA(4); issueA(5);

#pragma unroll
  for (int s = 0; s < NST; ++s) {
    if (s == NST - 1)       WAITVM(0);
    else if (s <= 1)        WAITVM(9);
    else if (s <= NST - 6)  WAITVM(6);
    else if (s == NST - 5)  WAITVM(5);
    else                    WAITVM(4);
    pin(ab[s % 6]);
#pragma unroll
    for (int i = 0; i < 4; ++i) pin(bb[s & 1][i]);
    u16* sAb = sA + (s & 1) * 5120;
    {  // predecode 4 int8 -> 4 bf16, write 8 B to champion LDS layout
      unsigned av = ab[s % 6];
      u32x2 w0;
      w0[0] = pk2(av, 0); w0[1] = pk2(av, 2);
      *(u32x2*)(sAb + (chA * 64 + rr) * 40 + seg * 4) = w0;
    }
    __syncthreads();  // one barrier/stage; double buffer covers the rest
#pragma unroll
    for (int ch = 0; ch < 2; ++ch)
#pragma unroll
      for (int mr = 0; mr < 2; ++mr) {
        const s16x8 ah =
            *(const s16x8*)(sAb + (ch * 64 + w_m * 32 + mr * 16 + r) * 40 + q * 8);
        acc[mr] = mfma_bf16(ah, bb[s & 1][ch * 2 + 0], acc[mr]);   // B hi
        acc[mr] = mfma_bf16(ah, bb[s & 1][ch * 2 + 1], acc[mr]);   // B lo
      }
    if (s + 2 < NST) issueB(s + 2);
    if (s + 6 < NST) issueA(s + 6);
  }

  if (HASX) {  // extra K=16 chunk from x_t (bf16-hi, padded to 32); weights chunk 16
#pragma unroll
    for (int mr = 0; mr < 2; ++mr) {
      s16x8 axh;
#pragma unroll
      for (int j = 0; j < 8; ++j) axh[j] = 0;
      if (q < 2) {
        const float* xp =
            P.x + (((long)(m0 + w_m * 32 + mr * 16 + r) * 336 + t) * 16 + q * 8);
        float4 v0 = *(const float4*)xp;
        float4 v1 = *(const float4*)(xp + 4);
        float vv[8] = {v0.x, v0.y, v0.z, v0.w, v1.x, v1.y, v1.z, v1.w};
#pragma unroll
        for (int j = 0; j < 8; ++j) axh[j] = (short)f2bf(vv[j]);
      }
      long bo = ((long)16 * 2048 + n0 + w_n * 16 + r) * 32 + q * 8;
      acc[mr] = mfma_bf16(axh, *(const s16x8*)(WBh + bo), acc[mr]);
      acc[mr] = mfma_bf16(axh, *(const s16x8*)(WBl + bo), acc[mr]);
    }
  }

  // ---- epilogue: gates -> (c,h); cols gate-interleaved n'=h*4+g ----
  __syncthreads();
  float* gbuf = (float*)smem;  // [64][132] fp32, float4-aligned conflict-free
#pragma unroll
  for (int mr = 0; mr < 2; ++mr)
#pragma unroll
    for (int reg = 0; reg < 4; ++reg)
      gbuf[(w_m * 32 + mr * 16 + q * 4 + reg) * 132 + (w_n * 16 + r)] = acc[mr][reg];
  __syncthreads();
  u8 hbv[2];
#pragma unroll
  for (int kk2 = 0; kk2 < 2; ++kk2) {
    int p = tid + kk2 * 1024;  // 0..2047 -> (row ml, 4-col group hl2)
    int ml = p >> 5, hl2 = p & 31;
    f32x4 g4 = *(const f32x4*)(gbuf + ml * 132 + hl2 * 4);
    int nb = n0 + hl2 * 4;
    float g0 = g4[0] + bias_p[nb + 0];
    float g1 = g4[1] + bias_p[nb + 1];
    float g2 = g4[2] + bias_p[nb + 2];
    float g3 = g4[3] + bias_p[nb + 3];
    if (HASY) {
      float yv = yb[ml];
      g0 += yv * wyp[nb + 0];
      g1 += yv * wyp[nb + 1];
      g2 += yv * wyp[nb + 2];
      g3 += yv * wyp[nb + 3];
    }
    float ig = sigm(g0), fg = sigm(g1), gg = tanhf(g2), og = sigm(g3);
    float cn = fg * creg[kk2] + ig * gg;
    creg[kk2] = cn;
    int qi = __float2int_rn(og * tanhf(cn) * 128.f);
    qi = qi > 127 ? 127 : (qi < -127 ? -127 : qi);
    hbv[kk2] = (u8)qi;
  }
  __syncthreads();
  u8* lh = (u8*)smem;  // [64][48] int8 (48: 16B-aligned rows)
#pragma unroll
  for (int kk2 = 0; kk2 < 2; ++kk2) {
    int p = tid + kk2 * 1024;
    lh[(p >> 5) * 48 + (p & 31)] = hbv[kk2];
  }
  __syncthreads();
  if (tid < 128) {  // 64 rows x 32 B
    int rw = tid >> 1, sg = tid & 1;
    st_sc1_x4(Hh + (n_tile * 1024 + m0 + rw) * 32 + sg * 16,
              *(const u32x4*)(lh + rw * 48 + sg * 16));
  }
}

// ---------------- FC head (fused into dec0 phase, own 64 rows, all blocks) ----
// y = relu(relu(h1@W1^T+b1)@W2^T+b2). Two K=256 passes through 24 KB LDS.
__device__ __forceinline__ void fc_inline(const KParams& P, int m_tile, int n_tile,
                                          const u8* Ah, int tOut, char* smem) {
  const int tid = threadIdx.x;
  const int w = tid >> 6, lane = tid & 63, r = lane & 15, q = lane >> 4;
  const int m0 = m_tile * 64;
  u8* sF = (u8*)smem;  // [8ch][64r][48 B] = 24576
  f32x4 af[4];         // wave w covers col w*16 + r (16 waves x 16 = 256)
#pragma unroll
  for (int mr = 0; mr < 4; ++mr) af[mr] = (f32x4){0.f, 0.f, 0.f, 0.f};

  u32x4 v1, v2;
  {
    int c = tid >> 7, rw = (tid >> 1) & 63, sg = tid & 1;
    v1 = ld_sc1_x4(Ah + c * 32768 + (m0 + rw) * 32 + sg * 16);
    v2 = ld_sc1_x4(Ah + (c + 8) * 32768 + (m0 + rw) * 32 + sg * 16);
  }
  WAITVM(1);
  pin(v1);
  {
    int c = tid >> 7, rw = (tid >> 1) & 63, sg = tid & 1;
    *(u32x4*)(sF + (c * 64 + rw) * 48 + sg * 16) = v1;
  }
  __syncthreads();
#pragma unroll
  for (int pass = 0; pass < 2; ++pass) {
    for (int c = 0; c < 8; ++c)
#pragma unroll
      for (int mr = 0; mr < 4; ++mr) {
        const s16x8 ah = unpk8(*(const u32x2*)(sF + (c * 64 + mr * 16 + r) * 48 + q * 8));
        int col = w * 16 + r;
        af[mr] = mfma_bf16(
            ah, *(const s16x8*)(P.wfh + ((pass * 8 + c) * 256 + col) * 32 + q * 8),
            af[mr]);
      }
    if (pass == 0) {
      wait_vm0();
      pin(v2);
      __syncthreads();
      {
        int c = tid >> 7, rw = (tid >> 1) & 63, sg = tid & 1;
        *(u32x4*)(sF + (c * 64 + rw) * 48 + sg * 16) = v2;
      }
      __syncthreads();
    }
  }
  __syncthreads();
  u16* hidb = (u16*)smem;  // [64][264] bf16
#pragma unroll
  for (int mr = 0; mr < 4; ++mr)
#pragma unroll
    for (int reg = 0; reg < 4; ++reg) {
      int row = mr * 16 + q * 4 + reg, col = w * 16 + r;
      hidb[row * 264 + col] = f2bf(fmaxf(af[mr][reg] + P.fcb1[col], 0.f));
    }
  __syncthreads();
  float* part = (float*)(smem + 33792);  // [64][5]
  if (tid < 256) {
    int m = tid >> 2, sg = tid & 3;
    float s = 0.f;
#pragma unroll
    for (int j = 0; j < 64; ++j)
      s += bf2f(hidb[m * 264 + sg * 64 + j]) * P.fcw2[sg * 64 + j];
    part[m * 5 + sg] = s;
  }
  __syncthreads();
  float* yb = (float*)(smem + 40960);  // [64], consumed by dec0 epilogue
  if (tid < 64) {
    float s = P.fcb2[0] + part[tid * 5 + 0] + part[tid * 5 + 1] +
              part[tid * 5 + 2] + part[tid * 5 + 3];
    float pred = fmaxf(s, 0.f);
    yb[tid] = pred;
    if (n_tile == 0) P.out[(long)(m0 + tid) * 168 + tOut] = pred;
  }
  __syncthreads();
}

// ---------------- persistent kernel ----------------
__global__ void __launch_bounds__(TPB, 4) lstm_seq(KParams P) {
  __shared__ __align__(16) char smem[41216];
  const int b = blockIdx.x;
  const int grp = b & 7;                   // XCD (round-robin dispatch at 1/CU)
  const int idx = b >> 3;                  // 0..31
  const int n_tile = grp * 2 + (idx & 1);  // 2 slabs/XCD -> ~3.1 MB L2-resident weights
  const int m_tile = idx >> 1;             // 0..15 = barrier group (16 blocks: all n)
  const float* yb = (const float*)(smem + 40960);
  unsigned long long bi = 0;
  int p0 = 0, p1 = 0;
  float c0r[2], c1r[2];
#pragma unroll
  for (int i = 0; i < 2; ++i) { c0r[i] = 0.f; c1r[i] = 0.f; }

  // encoder, layer-pipelined: phase p computes enc0(t=p) and enc1(t=p-1)
  for (int p = 0; p <= 336; ++p) {
    if (p < 336)
      lstm_phase<16, false, true, false>(P, m_tile, n_tile, P.h0h[p0], nullptr,
                                         P.we0h, P.we0l, P.be0, nullptr, p, c0r,
                                         P.h0h[p0 ^ 1], smem, nullptr);
    if (p >= 1)
      lstm_phase<32, true, false, false>(P, m_tile, n_tile, P.h0h[p0], P.h1h[p1],
                                         P.we1h, P.we1l, P.be1, nullptr, 0, c1r,
                                         P.h1h[p1 ^ 1], smem, nullptr);
    if (p < 336) p0 ^= 1;
    if (p >= 1) p1 ^= 1;
    ++bi; gbar(P, m_tile, bi);
  }
  // decoder: phase A = [fc(t-1) + dec0(t)], phase B = dec1(t); 2 barriers/step
  for (int t = 0; t < 168; ++t) {
    if (t > 0) {
      fc_inline(P, m_tile, n_tile, P.h1h[p1], t - 1, smem);
    } else {
      if (threadIdx.x < 64) ((float*)(smem + 40960))[threadIdx.x] = 0.f;
      __syncthreads();
    }
    lstm_phase<16, false, false, true>(P, m_tile, n_tile, P.h0h[p0], nullptr,
                                       P.wd0h, P.wd0l, P.bd0, P.wyp, 0, c0r,
                                       P.h0h[p0 ^ 1], smem, yb);
    p0 ^= 1; ++bi; gbar(P, m_tile, bi);
    lstm_phase<32, true, false, false>(P, m_tile, n_tile, P.h0h[p0], P.h1h[p1],
                                       P.wd1h, P.wd1l, P.bd1, nullptr, 0, c1r,
                                       P.h1h[p1 ^ 1], smem, nullptr);
    p1 ^= 1; ++bi; gbar(P, m_tile, bi);
  }
  fc_inline(P, m_tile, n_tile, P.h1h[p1], 167, smem);  // trailing fc
}

// ---------------- host ----------------
extern "C" void kernel_launch(void* const* d_in, const int* in_sizes, int n_in,
                              void* d_out, int out_size, void* d_ws, size_t ws_size,
                              hipStream_t stream) {
  const float* x     = (const float*)d_in[0];
  const float* eWih0 = (const float*)d_in[1];
  const float* eWhh0 = (const float*)d_in[2];
  const float* eb0   = (const float*)d_in[3];
  const float* eWih1 = (const float*)d_in[4];
  const float* eWhh1 = (const float*)d_in[5];
  const float* eb1   = (const float*)d_in[6];
  const float* dWih0 = (const float*)d_in[7];
  const float* dWhh0 = (const float*)d_in[8];
  const float* db0   = (const float*)d_in[9];
  const float* dWih1 = (const float*)d_in[10];
  const float* dWhh1 = (const float*)d_in[11];
  const float* db1   = (const float*)d_in[12];
  const float* fcW1  = (const float*)d_in[13];
  const float* fcb1  = (const float*)d_in[14];
  const float* fcW2  = (const float*)d_in[15];
  const float* fcb2  = (const float*)d_in[16];

  char* ws = (char*)d_ws;
  unsigned long long* cx = (unsigned long long*)(ws + 0);     // 16 groups x 256 B
  unsigned long long* cg = (unsigned long long*)(ws + 4096);  // unused
  char* hb = ws + 8192;
  u8* h0h0 = (u8*)(hb + 0L * 1048576);   // int8 h buffers: 512 KB used of 1 MB slot
  u8* h0h1 = (u8*)(hb + 1L * 1048576);
  u8* h1h0 = (u8*)(hb + 2L * 1048576);
  u8* h1h1 = (u8*)(hb + 3L * 1048576);
  char* wb = hb + 4L * 1048576;
  u16* we0h = (u16*)wb; wb += 2228224L;
  u16* we0l = (u16*)wb; wb += 2228224L;
  u16* we1h = (u16*)wb; wb += 4194304L;
  u16* we1l = (u16*)wb; wb += 4194304L;
  u16* wd0h = (u16*)wb; wb += 2097152L;
  u16* wd0l = (u16*)wb; wb += 2097152L;
  u16* wd1h = (u16*)wb; wb += 4194304L;
  u16* wd1l = (u16*)wb; wb += 4194304L;
  u16* wfh  = (u16*)wb; wb += 262144L;
  float* be0 = (float*)wb; wb += 8192L;
  float* be1 = (float*)wb; wb += 8192L;
  float* bd0 = (float*)wb; wb += 8192L;
  float* bd1 = (float*)wb; wb += 8192L;
  float* wyp = (float*)wb; wb += 8192L;

  long zbytes = 8192L + 4L * 1048576L;  // barrier counters + h ping-pong buffers
  zero_ws<<<1024, 256, 0, stream>>>((uint4*)ws, zbytes / 16);
  prep_w<<<2048, 256, 0, stream>>>(eWih0, eWhh0, eb0, we0h, we0l, be0, nullptr, 0, 17);
  prep_w<<<2048, 256, 0, stream>>>(eWih1, eWhh1, eb1, we1h, we1l, be1, nullptr, 1, 32);
  prep_w<<<2048, 256, 0, stream>>>(dWih0, dWhh0, db0, wd0h, wd0l, bd0, wyp, 2, 16);
  prep_w<<<2048, 256, 0, stream>>>(dWih1, dWhh1, db1, wd1h, wd1l, bd1, nullptr, 1, 32);
  prep_fc<<<512, 256, 0, stream>>>(fcW1, wfh);

  KParams P;
  P.x = x; P.out = (float*)d_out; P.cx = cx; P.cg = cg;
  P.h0h[0] = h0h0; P.h0h[1] = h0h1;
  P.h1h[0] = h1h0; P.h1h[1] = h1h1;
  P.we0h = we0h; P.we0l = we0l; P.we1h = we1h; P.we1l = we1l;
  P.wd0h = wd0h; P.wd0l = wd0l; P.wd1h = wd1h; P.wd1l = wd1l;
  P.wfh = wfh;
  P.be0 = be0; P.be1 = be1; P.bd0 = bd0; P.bd1 = bd1; P.wyp = wyp;
  P.fcb1 = fcb1; P.fcw2 = fcW2; P.fcb2 = fcb2;

  lstm_seq<<<NBLK, TPB, 0, stream>>>(P);
}

// Round 11
// 21002.963 us; speedup vs baseline: 1.4451x; 1.4451x over previous
//
#include <hip/hip_runtime.h>
#include <math.h>

#define TPB 1024
#define NBLK 256

typedef unsigned short u16;
typedef unsigned char u8;
typedef float f32x4 __attribute__((ext_vector_type(4)));
typedef short s16x8 __attribute__((ext_vector_type(8)));
typedef unsigned int u32x4 __attribute__((ext_vector_type(4)));
typedef unsigned int u32x2 __attribute__((ext_vector_type(2)));

// ---------------- helpers ----------------
__device__ __forceinline__ u16 f2bf(float f) {
  unsigned u = __float_as_uint(f);
  unsigned r = (u + 0x7FFFu + ((u >> 16) & 1u)) >> 16;   // RNE
  return (u16)r;
}
__device__ __forceinline__ float bf2f(u16 b) { return __uint_as_float(((unsigned)b) << 16); }
__device__ __forceinline__ float sigm(float x) { return 1.f / (1.f + expf(-x)); }

__device__ __forceinline__ f32x4 mfma_bf16(s16x8 a, s16x8 b, f32x4 c) {
  return __builtin_amdgcn_mfma_f32_16x16x32_bf16(a, b, c, 0, 0, 0);
}

// int8 fixed-point h: q = rint(h*128), |h|<1. Decode q/128 is EXACT in bf16.
__device__ __forceinline__ unsigned pk2(unsigned wd, int j) {
  int b0 = ((int)(wd << ((3 - j) * 8))) >> 24;
  int b1 = ((int)(wd << ((2 - j) * 8))) >> 24;
  float f0 = (float)b0 * 0.0078125f;
  float f1 = (float)b1 * 0.0078125f;
  return (__float_as_uint(f0) >> 16) | (__float_as_uint(f1) & 0xFFFF0000u);
}
__device__ __forceinline__ s16x8 unpk8(u32x2 wv) {  // fc head only
  s16x8 o;
#pragma unroll
  for (int j = 0; j < 4; ++j) {
    int b0 = ((int)(wv[0] << ((3 - j) * 8))) >> 24;
    float f0 = (float)b0 * 0.0078125f;
    o[j] = (short)(__float_as_uint(f0) >> 16);
    int b1 = ((int)(wv[1] << ((3 - j) * 8))) >> 24;
    float f1 = (float)b1 * 0.0078125f;
    o[4 + j] = (short)(__float_as_uint(f1) >> 16);
  }
  return o;
}

// ---- asm memory ops. sc1 = device scope (meet at LLC); plain = cached.
__device__ __forceinline__ u32x4 ld_sc1_x4(const void* p) {
  u32x4 d;
  asm volatile("global_load_dwordx4 %0, %1, off sc1"
               : "=v"(d) : "v"((unsigned long long)p) : "memory");
  return d;
}
__device__ __forceinline__ unsigned ld_sc1_x1(const void* p) {
  unsigned d;
  asm volatile("global_load_dword %0, %1, off sc1"
               : "=v"(d) : "v"((unsigned long long)p) : "memory");
  return d;
}
__device__ __forceinline__ u32x4 ld_c_x4(const void* p) {  // cached (weights)
  u32x4 d;
  asm volatile("global_load_dwordx4 %0, %1, off"
               : "=v"(d) : "v"((unsigned long long)p) : "memory");
  return d;
}
__device__ __forceinline__ void st_sc1_x4(void* p, u32x4 v) {
  asm volatile("global_store_dwordx4 %0, %1, off sc1"
               :: "v"((unsigned long long)p), "v"(v) : "memory");
}
__device__ __forceinline__ void wait_vm0() { asm volatile("s_waitcnt vmcnt(0)" ::: "memory"); }
#define WAITVM(n) asm volatile("s_waitcnt vmcnt(" #n ")" ::: "memory")
__device__ __forceinline__ void pin(u32x4& v) { asm volatile("" : "+v"(v)); }
__device__ __forceinline__ void pin(unsigned& v) { asm volatile("" : "+v"(v)); }
__device__ __forceinline__ void pin(s16x8& v) { asm volatile("" : "+v"(v)); }

// ---------------- params ----------------
struct KParams {
  const float* x;          // [1024][336][16]
  float* out;              // [1024][168]
  unsigned long long* cx;  // per-M-GROUP barrier counters (16 groups, stride 256B)
  unsigned long long* cg;  // unused
  u8* h0h[2]; u8* h1h[2];  // h int8 fixed-point [16 ch][1024 r][32 B], ping-pong (sc1)
  const u16 *we0h, *we0l;  // [17][2048][32] (chunk 16 = x weights)
  const u16 *we1h, *we1l;  // [32][2048][32]
  const u16 *wd0h, *wd0l;  // [16][2048][32]
  const u16 *wd1h, *wd1l;  // [32][2048][32]
  const u16 *wfh;          // [16][256][32] (hi only)
  const float *be0, *be1, *bd0, *bd1, *wyp;  // permuted biases [2048], dec0 y-column [2048]
  const float *fcb1, *fcw2, *fcb2;           // raw fp32 from inputs
};

// ---------------- init kernels ----------------
__global__ void zero_ws(uint4* p, long n) {
  uint4 z = {0u, 0u, 0u, 0u};
  for (long i = (long)blockIdx.x * blockDim.x + threadIdx.x; i < n; i += (long)gridDim.x * blockDim.x)
    p[i] = z;
}

// Build fragment-major, gate-interleaved, hi/lo-split weights.
// dst[c][n'][kk], n' = h*4+g  (orig row n = g*512+h), k = c*32+kk.
__global__ void prep_w(const float* __restrict__ Wih, const float* __restrict__ Whh,
                       const float* __restrict__ bias,
                       u16* __restrict__ dhi, u16* __restrict__ dlo,
                       float* __restrict__ bias_p, float* __restrict__ wy_p,
                       int mode, int nchunks) {
  long total = (long)nchunks * 2048 * 32;
  for (long i = (long)blockIdx.x * blockDim.x + threadIdx.x; i < total; i += (long)gridDim.x * blockDim.x) {
    int kk = (int)(i & 31);
    long r1 = i >> 5;
    int n = (int)(r1 & 2047);
    int c = (int)(r1 >> 11);
    int h = n >> 2, g = n & 3;
    int no = g * 512 + h;
    float wv;
    if (mode == 0)      wv = (c < 16) ? Whh[no * 512 + c * 32 + kk] : (kk < 16 ? Wih[no * 16 + kk] : 0.f);
    else if (mode == 1) wv = (c < 16) ? Wih[no * 512 + c * 32 + kk] : Whh[no * 512 + (c - 16) * 32 + kk];
    else                wv = Whh[no * 512 + c * 32 + kk];
    u16 hb = f2bf(wv);
    dhi[i] = hb;
    dlo[i] = f2bf(wv - bf2f(hb));
    if (i < 2048) {
      int nn = (int)i, hh = nn >> 2, gg = nn & 3, noo = gg * 512 + hh;
      bias_p[nn] = bias[noo];
      if (mode == 2) wy_p[nn] = Wih[noo];  // dec_Wih0 is [2048][1]
    }
  }
}

__global__ void prep_fc(const float* __restrict__ W1, u16* __restrict__ dhi) {
  int total = 16 * 256 * 32;
  for (int i = blockIdx.x * blockDim.x + threadIdx.x; i < total; i += gridDim.x * blockDim.x) {
    int kk = i & 31, n = (i >> 5) & 255, c = i >> 13;
    dhi[i] = f2bf(W1[n * 512 + c * 32 + kk]);
  }
}

// ------------- m-group barrier: 16 blocks (all n-tiles of one m-tile) -------------
// All cross-block deps are m-row-local (verified r7).
__device__ __forceinline__ void gbar(const KParams& P, int mgrp, unsigned long long bi) {
  wait_vm0();       // this wave's sc1 stores are at the LLC
  __syncthreads();  // all 16 waves drained
  if (threadIdx.x == 0) {
    unsigned long long* ctr = &P.cx[mgrp * 32];
    __hip_atomic_fetch_add(ctr, 1ULL, __ATOMIC_RELAXED, __HIP_MEMORY_SCOPE_AGENT);
    unsigned long long t0 = __builtin_amdgcn_s_memrealtime();
    while (__hip_atomic_load(ctr, __ATOMIC_RELAXED, __HIP_MEMORY_SCOPE_AGENT) < bi * 16ULL) {
      __builtin_amdgcn_s_sleep(2);
      if (__builtin_amdgcn_s_memrealtime() - t0 > 300000000ULL) {  // ~3 s
        P.out[0] = 1e9f;  // sentinel: barrier timeout
        break;
      }
    }
  }
  __syncthreads();
}

// ---------------- fused gates GEMM + LSTM cell ----------------
// 64m x 128n tile, 256 blocks, 1024 threads (4 waves/SIMD = r10's 49% occ,
// which demonstrated 1.77 TB/s beyond-L2 delivery). r10's regression was
// FETCH 3x: the two m-wave-groups each issued the full B stream, and at 4
// waves/SIMD the temporally-spread duplicate requests missed L1/L2 (+32 GB
// -- same signature as r1/r2/r3). Fix: B staged through LDS like A -- each
// 32 KB B-tile (2 chunks, hi+lo) is loaded from global exactly ONCE per
// block per stage (2 cached dwordx4/thread) and all 16 waves read fragments
// from LDS. B rows stay 64 B (aligned b128) with slot XOR-swizzle
// (slot = q ^ (r&3)) cutting read conflicts 8-way -> 4-way.
// Per stage/thread: 1 A (dword sc1) + 2 B (dwordx4 cached). FIFO vmcnt by
// full queue simulation (prologue A0 B0 B0 A1 B1 B1 A2..A5; stage s issues
// B(s+2) x2, A(s+6)): s<=1:7; s<=NST-6:4; s==NST-5:3; else 2; last 0.
template <int NCT, bool TWOA, bool HASX, bool HASY>
__device__ __forceinline__ void lstm_phase(
    const KParams& P, int m_tile, int n_tile,
    const u8* A1h, const u8* A2h,
    const u16* WBh, const u16* WBl,
    const float* __restrict__ bias_p, const float* __restrict__ wyp, int t,
    float (&creg)[2], u8* Hh, char* smem, const float* yb) {
  constexpr int NST = NCT / 2;
  const int tid = threadIdx.x;
  const int w = tid >> 6, lane = tid & 63, r = lane & 15, q = lane >> 4;
  const int w_m = w >> 3, w_n = w & 7;
  const int m0 = m_tile * 64, n0 = n_tile * 128;
  u16* sA = (u16*)smem;            // 2 bufs x [2ch][64r][40 u16] = 20480 B
  char* sB = smem + 20480;         // 2 bufs x [2ch*2hl][128c][64 B] = 65536 B
  const int rr = (tid >> 3) & 63, seg = tid & 7, chA = tid >> 9;
  // B staging decomposition: idx=tid*2+j -> part(16B)=idx&3, col=(idx>>2)&127,
  // hl=(idx>>9)&1, chB=idx>>10. tid*2 even => col/hl/chB shared by j=0,1.
  const int colB = (tid >> 1) & 127, hlB = (tid >> 8) & 1, chB = tid >> 9;
  const int p0 = (tid & 1) * 2;
  const u16* wpB = hlB ? WBl : WBh;
  const long bge = (long)(n0 + colB) * 32 + p0 * 8;   // u16; + c*65536
  const int XB = (chB * 2 + hlB) * 128 + colB;
  const int bl0 = XB * 64 + ((p0 ^ (colB & 3)) * 16);        // swizzled slots
  const int bl1 = XB * 64 + (((p0 + 1) ^ (colB & 3)) * 16);

  f32x4 acc[2];
#pragma unroll
  for (int mr = 0; mr < 2; ++mr) acc[mr] = (f32x4){0.f, 0.f, 0.f, 0.f};

  unsigned ab[6];   // A 6-stage lookahead, 1 dword (4 int8)/thread/stage
  u32x4 bs[2][2];   // B 2-stage lookahead (raw 16 B each)
  const int a_elem = (m0 + rr) * 32 + seg * 4;  // bytes; + chunk*32768

  auto issueA = [&](int s) {
    int c = s * 2 + chA;
    const u8* base = A1h;
    if (TWOA && c >= 16) { base = A2h; c -= 16; }
    ab[s % 6] = ld_sc1_x1(base + c * 32768 + a_elem);
  };
  auto issueB = [&](int s) {
    const u16* p = wpB + (long)(s * 2 + chB) * 65536 + bge;
    bs[s & 1][0] = ld_c_x4(p);
    bs[s & 1][1] = ld_c_x4(p + 8);
  };

  // prologue; FIFO order: A0 B0(2) A1 B1(2) A2 A3 A4 A5  (10 in flight)
  issueA(0); issueB(0); issueA(1); issueB(1);
  issueA(2); issueA(3); issueA(4); issueA(5);

#pragma unroll
  for (int s = 0; s < NST; ++s) {
    if (s == NST - 1)       WAITVM(0);
    else if (s <= 1)        WAITVM(7);
    else if (s <= NST - 6)  WAITVM(4);
    else if (s == NST - 5)  WAITVM(3);
    else                    WAITVM(2);
    pin(ab[s % 6]); pin(bs[s & 1][0]); pin(bs[s & 1][1]);
    u16* sAb = sA + (s & 1) * 5120;
    char* sBb = sB + (s & 1) * 32768;
    {  // predecode 4 int8 -> 4 bf16, write 8 B to A LDS layout
      unsigned av = ab[s % 6];
      u32x2 w0;
      w0[0] = pk2(av, 0); w0[1] = pk2(av, 2);
      *(u32x2*)(sAb + (chA * 64 + rr) * 40 + seg * 4) = w0;
    }
    {  // write B tile (raw bf16), swizzled slots
      *(u32x4*)(sBb + bl0) = bs[s & 1][0];
      *(u32x4*)(sBb + bl1) = bs[s & 1][1];
    }
    __syncthreads();  // one barrier/stage; double buffer covers the rest
    s16x8 bf[2][2];
#pragma unroll
    for (int ch = 0; ch < 2; ++ch)
#pragma unroll
      for (int hl = 0; hl < 2; ++hl)
        bf[ch][hl] = *(const s16x8*)(
            sBb + ((ch * 2 + hl) * 128 + w_n * 16 + r) * 64 + ((q ^ (r & 3)) * 16));
#pragma unroll
    for (int ch = 0; ch < 2; ++ch)
#pragma unroll
      for (int mr = 0; mr < 2; ++mr) {
        const s16x8 ah =
            *(const s16x8*)(sAb + (ch * 64 + w_m * 32 + mr * 16 + r) * 40 + q * 8);
        acc[mr] = mfma_bf16(ah, bf[ch][0], acc[mr]);   // B hi
        acc[mr] = mfma_bf16(ah, bf[ch][1], acc[mr]);   // B lo
      }
    if (s + 2 < NST) issueB(s + 2);
    if (s + 6 < NST) issueA(s + 6);
  }

  if (HASX) {  // extra K=16 chunk from x_t (bf16-hi, padded to 32); weights chunk 16
#pragma unroll
    for (int mr = 0; mr < 2; ++mr) {
      s16x8 axh;
#pragma unroll
      for (int j = 0; j < 8; ++j) axh[j] = 0;
      if (q < 2) {
        const float* xp =
            P.x + (((long)(m0 + w_m * 32 + mr * 16 + r) * 336 + t) * 16 + q * 8);
        float4 v0 = *(const float4*)xp;
        float4 v1 = *(const float4*)(xp + 4);
        float vv[8] = {v0.x, v0.y, v0.z, v0.w, v1.x, v1.y, v1.z, v1.w};
#pragma unroll
        for (int j = 0; j < 8; ++j) axh[j] = (short)f2bf(vv[j]);
      }
      long bo = ((long)16 * 2048 + n0 + w_n * 16 + r) * 32 + q * 8;
      acc[mr] = mfma_bf16(axh, *(const s16x8*)(WBh + bo), acc[mr]);
      acc[mr] = mfma_bf16(axh, *(const s16x8*)(WBl + bo), acc[mr]);
    }
  }

  // ---- epilogue: gates -> (c,h); cols gate-interleaved n'=h*4+g ----
  __syncthreads();
  float* gbuf = (float*)smem;  // [64][132] fp32, float4-aligned conflict-free
#pragma unroll
  for (int mr = 0; mr < 2; ++mr)
#pragma unroll
    for (int reg = 0; reg < 4; ++reg)
      gbuf[(w_m * 32 + mr * 16 + q * 4 + reg) * 132 + (w_n * 16 + r)] = acc[mr][reg];
  __syncthreads();
  u8 hbv[2];
#pragma unroll
  for (int kk2 = 0; kk2 < 2; ++kk2) {
    int p = tid + kk2 * 1024;  // 0..2047 -> (row ml, 4-col group hl2)
    int ml = p >> 5, hl2 = p & 31;
    f32x4 g4 = *(const f32x4*)(gbuf + ml * 132 + hl2 * 4);
    int nb = n0 + hl2 * 4;
    float g0 = g4[0] + bias_p[nb + 0];
    float g1 = g4[1] + bias_p[nb + 1];
    float g2 = g4[2] + bias_p[nb + 2];
    float g3 = g4[3] + bias_p[nb + 3];
    if (HASY) {
      float yv = yb[ml];
      g0 += yv * wyp[nb + 0];
      g1 += yv * wyp[nb + 1];
      g2 += yv * wyp[nb + 2];
      g3 += yv * wyp[nb + 3];
    }
    float ig = sigm(g0), fg = sigm(g1), gg = tanhf(g2), og = sigm(g3);
    float cn = fg * creg[kk2] + ig * gg;
    creg[kk2] = cn;
    int qi = __float2int_rn(og * tanhf(cn) * 128.f);
    qi = qi > 127 ? 127 : (qi < -127 ? -127 : qi);
    hbv[kk2] = (u8)qi;
  }
  __syncthreads();
  u8* lh = (u8*)smem;  // [64][48] int8 (48: 16B-aligned rows)
#pragma unroll
  for (int kk2 = 0; kk2 < 2; ++kk2) {
    int p = tid + kk2 * 1024;
    lh[(p >> 5) * 48 + (p & 31)] = hbv[kk2];
  }
  __syncthreads();
  if (tid < 128) {  // 64 rows x 32 B
    int rw = tid >> 1, sg = tid & 1;
    st_sc1_x4(Hh + (n_tile * 1024 + m0 + rw) * 32 + sg * 16,
              *(const u32x4*)(lh + rw * 48 + sg * 16));
  }
}

// ---------------- FC head (fused into dec0 phase, own 64 rows, all blocks) ----
// y = relu(relu(h1@W1^T+b1)@W2^T+b2). Two K=256 passes through 24 KB LDS.
__device__ __forceinline__ void fc_inline(const KParams& P, int m_tile, int n_tile,
                                          const u8* Ah, int tOut, char* smem) {
  const int tid = threadIdx.x;
  const int w = tid >> 6, lane = tid & 63, r = lane & 15, q = lane >> 4;
  const int m0 = m_tile * 64;
  u8* sF = (u8*)smem;  // [8ch][64r][48 B] = 24576
  f32x4 af[4];         // wave w covers col w*16 + r (16 waves x 16 = 256)
#pragma unroll
  for (int mr = 0; mr < 4; ++mr) af[mr] = (f32x4){0.f, 0.f, 0.f, 0.f};

  u32x4 v1, v2;
  {
    int c = tid >> 7, rw = (tid >> 1) & 63, sg = tid & 1;
    v1 = ld_sc1_x4(Ah + c * 32768 + (m0 + rw) * 32 + sg * 16);
    v2 = ld_sc1_x4(Ah + (c + 8) * 32768 + (m0 + rw) * 32 + sg * 16);
  }
  WAITVM(1);
  pin(v1);
  {
    int c = tid >> 7, rw = (tid >> 1) & 63, sg = tid & 1;
    *(u32x4*)(sF + (c * 64 + rw) * 48 + sg * 16) = v1;
  }
  __syncthreads();
#pragma unroll
  for (int pass = 0; pass < 2; ++pass) {
    for (int c = 0; c < 8; ++c)
#pragma unroll
      for (int mr = 0; mr < 4; ++mr) {
        const s16x8 ah = unpk8(*(const u32x2*)(sF + (c * 64 + mr * 16 + r) * 48 + q * 8));
        int col = w * 16 + r;
        af[mr] = mfma_bf16(
            ah, *(const s16x8*)(P.wfh + ((pass * 8 + c) * 256 + col) * 32 + q * 8),
            af[mr]);
      }
    if (pass == 0) {
      wait_vm0();
      pin(v2);
      __syncthreads();
      {
        int c = tid >> 7, rw = (tid >> 1) & 63, sg = tid & 1;
        *(u32x4*)(sF + (c * 64 + rw) * 48 + sg * 16) = v2;
      }
      __syncthreads();
    }
  }
  __syncthreads();
  u16* hidb = (u16*)smem;  // [64][264] bf16
#pragma unroll
  for (int mr = 0; mr < 4; ++mr)
#pragma unroll
    for (int reg = 0; reg < 4; ++reg) {
      int row = mr * 16 + q * 4 + reg, col = w * 16 + r;
      hidb[row * 264 + col] = f2bf(fmaxf(af[mr][reg] + P.fcb1[col], 0.f));
    }
  __syncthreads();
  float* part = (float*)(smem + 33792);  // [64][5]
  if (tid < 256) {
    int m = tid >> 2, sg = tid & 3;
    float s = 0.f;
#pragma unroll
    for (int j = 0; j < 64; ++j)
      s += bf2f(hidb[m * 264 + sg * 64 + j]) * P.fcw2[sg * 64 + j];
    part[m * 5 + sg] = s;
  }
  __syncthreads();
  float* yb = (float*)(smem + 40960);  // [64], consumed by dec0 epilogue
  if (tid < 64) {
    float s = P.fcb2[0] + part[tid * 5 + 0] + part[tid * 5 + 1] +
              part[tid * 5 + 2] + part[tid * 5 + 3];
    float pred = fmaxf(s, 0.f);
    yb[tid] = pred;
    if (n_tile == 0) P.out[(long)(m0 + tid) * 168 + tOut] = pred;
  }
  __syncthreads();
}

// ---------------- persistent kernel ----------------
__global__ void __launch_bounds__(TPB, 4) lstm_seq(KParams P) {
  __shared__ __align__(16) char smem[86016];  // A 20 KB + B 64 KB dbuf staging
  const int b = blockIdx.x;
  const int grp = b & 7;                   // XCD (round-robin dispatch at 1/CU)
  const int idx = b >> 3;                  // 0..31
  const int n_tile = grp * 2 + (idx & 1);  // 2 slabs/XCD -> ~3.1 MB L2-resident weights
  const int m_tile = idx >> 1;             // 0..15 = barrier group (16 blocks: all n)
  const float* yb = (const float*)(smem + 40960);
  unsigned long long bi = 0;
  int p0 = 0, p1 = 0;
  float c0r[2], c1r[2];
#pragma unroll
  for (int i = 0; i < 2; ++i) { c0r[i] = 0.f; c1r[i] = 0.f; }

  // encoder, layer-pipelined: phase p computes enc0(t=p) and enc1(t=p-1)
  for (int p = 0; p <= 336; ++p) {
    if (p < 336)
      lstm_phase<16, false, true, false>(P, m_tile, n_tile, P.h0h[p0], nullptr,
                                         P.we0h, P.we0l, P.be0, nullptr, p, c0r,
                                         P.h0h[p0 ^ 1], smem, nullptr);
    if (p >= 1)
      lstm_phase<32, true, false, false>(P, m_tile, n_tile, P.h0h[p0], P.h1h[p1],
                                         P.we1h, P.we1l, P.be1, nullptr, 0, c1r,
                                         P.h1h[p1 ^ 1], smem, nullptr);
    if (p < 336) p0 ^= 1;
    if (p >= 1) p1 ^= 1;
    ++bi; gbar(P, m_tile, bi);
  }
  // decoder: phase A = [fc(t-1) + dec0(t)], phase B = dec1(t); 2 barriers/step
  for (int t = 0; t < 168; ++t) {
    if (t > 0) {
      fc_inline(P, m_tile, n_tile, P.h1h[p1], t - 1, smem);
    } else {
      if (threadIdx.x < 64) ((float*)(smem + 40960))[threadIdx.x] = 0.f;
      __syncthreads();
    }
    lstm_phase<16, false, false, true>(P, m_tile, n_tile, P.h0h[p0], nullptr,
                                       P.wd0h, P.wd0l, P.bd0, P.wyp, 0, c0r,
                                       P.h0h[p0 ^ 1], smem, yb);
    p0 ^= 1; ++bi; gbar(P, m_tile, bi);
    lstm_phase<32, true, false, false>(P, m_tile, n_tile, P.h0h[p0], P.h1h[p1],
                                       P.wd1h, P.wd1l, P.bd1, nullptr, 0, c1r,
                                       P.h1h[p1 ^ 1], smem, nullptr);
    p1 ^= 1; ++bi; gbar(P, m_tile, bi);
  }
  fc_inline(P, m_tile, n_tile, P.h1h[p1], 167, smem);  // trailing fc
}

// ---------------- host ----------------
extern "C" void kernel_launch(void* const* d_in, const int* in_sizes, int n_in,
                              void* d_out, int out_size, void* d_ws, size_t ws_size,
                              hipStream_t stream) {
  const float* x     = (const float*)d_in[0];
  const float* eWih0 = (const float*)d_in[1];
  const float* eWhh0 = (const float*)d_in[2];
  const float* eb0   = (const float*)d_in[3];
  const float* eWih1 = (const float*)d_in[4];
  const float* eWhh1 = (const float*)d_in[5];
  const float* eb1   = (const float*)d_in[6];
  const float* dWih0 = (const float*)d_in[7];
  const float* dWhh0 = (const float*)d_in[8];
  const float* db0   = (const float*)d_in[9];
  const float* dWih1 = (const float*)d_in[10];
  const float* dWhh1 = (const float*)d_in[11];
  const float* db1   = (const float*)d_in[12];
  const float* fcW1  = (const float*)d_in[13];
  const float* fcb1  = (const float*)d_in[14];
  const float* fcW2  = (const float*)d_in[15];
  const float* fcb2  = (const float*)d_in[16];

  char* ws = (char*)d_ws;
  unsigned long long* cx = (unsigned long long*)(ws + 0);     // 16 groups x 256 B
  unsigned long long* cg = (unsigned long long*)(ws + 4096);  // unused
  char* hb = ws + 8192;
  u8* h0h0 = (u8*)(hb + 0L * 1048576);   // int8 h buffers: 512 KB used of 1 MB slot
  u8* h0h1 = (u8*)(hb + 1L * 1048576);
  u8* h1h0 = (u8*)(hb + 2L * 1048576);
  u8* h1h1 = (u8*)(hb + 3L * 1048576);
  char* wb = hb + 4L * 1048576;
  u16* we0h = (u16*)wb; wb += 2228224L;
  u16* we0l = (u16*)wb; wb += 2228224L;
  u16* we1h = (u16*)wb; wb += 4194304L;
  u16* we1l = (u16*)wb; wb += 4194304L;
  u16* wd0h = (u16*)wb; wb += 2097152L;
  u16* wd0l = (u16*)wb; wb += 2097152L;
  u16* wd1h = (u16*)wb; wb += 4194304L;
  u16* wd1l = (u16*)wb; wb += 4194304L;
  u16* wfh  = (u16*)wb; wb += 262144L;
  float* be0 = (float*)wb; wb += 8192L;
  float* be1 = (float*)wb; wb += 8192L;
  float* bd0 = (float*)wb; wb += 8192L;
  float* bd1 = (float*)wb; wb += 8192L;
  float* wyp = (float*)wb; wb += 8192L;

  long zbytes = 8192L + 4L * 1048576L;  // barrier counters + h ping-pong buffers
  zero_ws<<<1024, 256, 0, stream>>>((uint4*)ws, zbytes / 16);
  prep_w<<<2048, 256, 0, stream>>>(eWih0, eWhh0, eb0, we0h, we0l, be0, nullptr, 0, 17);
  prep_w<<<2048, 256, 0, stream>>>(eWih1, eWhh1, eb1, we1h, we1l, be1, nullptr, 1, 32);
  prep_w<<<2048, 256, 0, stream>>>(dWih0, dWhh0, db0, wd0h, wd0l, bd0, wyp, 2, 16);
  prep_w<<<2048, 256, 0, stream>>>(dWih1, dWhh1, db1, wd1h, wd1l, bd1, nullptr, 1, 32);
  prep_fc<<<512, 256, 0, stream>>>(fcW1, wfh);

  KParams P;
  P.x = x; P.out = (float*)d_out; P.cx = cx; P.cg = cg;
  P.h0h[0] = h0h0; P.h0h[1] = h0h1;
  P.h1h[0] = h1h0; P.h1h[1] = h1h1;
  P.we0h = we0h; P.we0l = we0l; P.we1h = we1h; P.we1l = we1l;
  P.wd0h = wd0h; P.wd0l = wd0l; P.wd1h = wd1h; P.wd1l = wd1l;
  P.wfh = wfh;
  P.be0 = be0; P.be1 = be1; P.bd0 = bd0; P.bd1 = bd1; P.wyp = wyp;
  P.fcb1 = fcb1; P.fcw2 = fcW2; P.fcb2 = fcb2;

  lstm_seq<<<NBLK, TPB, 0, stream>>>(P);
}